// Round 1
// baseline (626.467 us; speedup 1.0000x reference)
//
#include <hip/hip_runtime.h>
#include <math.h>

#define NB 32768
#define NC 1000
#define ND 512
#define NTILES 63          // 63*16 = 1008 >= 1000 class columns
#define PROWS 1024         // padded prototype rows stored in workspace
#define INV_T 10.0f        // 1/TEMPERATURE

typedef __attribute__((ext_vector_type(8))) short short8;
typedef __attribute__((ext_vector_type(4))) float f32x4;

__device__ __forceinline__ unsigned short bf16_rne(float f) {
    unsigned int u = __builtin_bit_cast(unsigned int, f);
    u += 0x7FFFu + ((u >> 16) & 1u);
    return (unsigned short)(u >> 16);
}

// ---------------- normalize prototypes -> bf16 [PROWS][ND] ----------------
__global__ __launch_bounds__(256) void norm_protos(const float* __restrict__ pro,
                                                   unsigned short* __restrict__ pbf) {
    const int row = blockIdx.x, t = threadIdx.x;
    unsigned int* dst = (unsigned int*)(pbf + (size_t)row * ND);
    if (row >= NC) { dst[t] = 0u; return; }  // zero pad rows (uniform per block)
    const float* rp = pro + (size_t)row * ND;
    const float x0 = rp[2 * t], x1 = rp[2 * t + 1];
    float ss = x0 * x0 + x1 * x1;
#pragma unroll
    for (int o = 1; o < 64; o <<= 1) ss += __shfl_xor(ss, o, 64);
    __shared__ float part[4];
    if ((t & 63) == 0) part[t >> 6] = ss;
    __syncthreads();
    const float nrm = sqrtf(part[0] + part[1] + part[2] + part[3]);
    const float sc = 1.0f / fmaxf(nrm, 1e-12f);
    dst[t] = (unsigned int)bf16_rne(x0 * sc) | ((unsigned int)bf16_rne(x1 * sc) << 16);
}

// ---------------- simloss: fused GEMM + online logsumexp ----------------
// Swapped MFMA: S^T = P_tile (A, 16x32) * F^T (B, 32x16) per K-step.
// D layout (m89-verified): col = lane&15 = feature row, row = (lane>>4)*4 + reg = class.
__global__ __launch_bounds__(256) void simloss_kernel(const float* __restrict__ feat,
                                                      const int* __restrict__ labels,
                                                      const unsigned short* __restrict__ pbf,
                                                      float* __restrict__ acc) {
    __shared__ short8 atile[1024];  // 16 KiB, fragment order [kk][g][r], linear per-lane reads
    const int t = threadIdx.x;
    const int wid = t >> 6, lane = t & 63;
    const int r16 = lane & 15, g = lane >> 4;
    const int brow = blockIdx.x * 64 + wid * 16 + r16;

    // Convert this lane's feature-row slice to bf16 fragments (held across all C tiles)
    short8 bfrag[16];
    const float* fp = feat + (size_t)brow * ND + 8 * g;
#pragma unroll
    for (int kk = 0; kk < 16; ++kk) {
        const float4* p = (const float4*)(fp + 32 * kk);
        const float4 a = p[0], b = p[1];
        const float v[8] = {a.x, a.y, a.z, a.w, b.x, b.y, b.z, b.w};
        short8 s;
#pragma unroll
        for (int i = 0; i < 8; ++i) s[i] = (short)bf16_rne(v[i]);
        bfrag[kk] = s;
    }

    int lab = labels[brow];
    lab = lab < 0 ? 0 : (lab > NC - 1 ? NC - 1 : lab);

    float m = -INFINITY, lsum = 0.f, labv = 0.f;

    for (int ct = 0; ct < NTILES; ++ct) {
        // Stage prototype tile (16 rows x 512 k, bf16) into LDS in fragment order.
#pragma unroll
        for (int q = 0; q < 4; ++q) {
            const int id = t + 256 * q;
            const int rr = id & 15, gg = (id >> 4) & 3, kk = id >> 6;
            atile[id] = *(const short8*)(pbf + (size_t)(ct * 16 + rr) * ND + 32 * kk + 8 * gg);
        }
        __syncthreads();
        f32x4 dacc = {0.f, 0.f, 0.f, 0.f};
#pragma unroll
        for (int kk = 0; kk < 16; ++kk)
            dacc = __builtin_amdgcn_mfma_f32_16x16x32_bf16(atile[kk * 64 + lane], bfrag[kk], dacc, 0, 0, 0);
        __syncthreads();  // protects atile for next iteration's staging

        const int cbase = ct * 16 + g * 4;
        float vv[4], tmax = -INFINITY;
#pragma unroll
        for (int rI = 0; rI < 4; ++rI) {
            const int c = cbase + rI;
            const float v = dacc[rI] * INV_T;
            const bool ok = (c < NC);
            if (ok && c == lab) labv += v;
            vv[rI] = ok ? v : -INFINITY;
            tmax = fmaxf(tmax, vv[rI]);
        }
        const float mnew = fmaxf(m, tmax);   // finite after first tile for every lane
        float add = 0.f;
#pragma unroll
        for (int rI = 0; rI < 4; ++rI) add += expf(vv[rI] - mnew);
        lsum = lsum * expf(m - mnew) + add;  // expf(-inf)=0 handles the first tile
        m = mnew;
    }

    // Combine the 4 lane-groups holding the same feature row (xor 16, xor 32)
#pragma unroll
    for (int o = 16; o <= 32; o <<= 1) {
        const float mo = __shfl_xor(m, o, 64);
        const float lo = __shfl_xor(lsum, o, 64);
        labv += __shfl_xor(labv, o, 64);
        const float mm = fmaxf(m, mo);
        lsum = lsum * expf(m - mm) + lo * expf(mo - mm);
        m = mm;
    }
    // Each row's value is now replicated on 4 lanes -> scale by 1/4, then mean over B
    float mine = (m + logf(lsum) - labv) * (1.0f / (4.0f * (float)NB));
#pragma unroll
    for (int o = 1; o < 64; o <<= 1) mine += __shfl_xor(mine, o, 64);
    if (lane == 0) atomicAdd(acc, mine);
}

// ---------------- cross-entropy over logits ----------------
__global__ __launch_bounds__(256) void ce_kernel(const float* __restrict__ logits,
                                                 const int* __restrict__ labels,
                                                 float* __restrict__ acc) {
    const int t = threadIdx.x, wid = t >> 6, lane = t & 63;
    const int row = blockIdx.x * 4 + wid;
    const float* rp = logits + (size_t)row * NC;
    float x[16];
#pragma unroll
    for (int j = 0; j < 4; ++j) {
        const int c0 = lane * 4 + j * 256;   // float4-granular; NC%4==0 so all-or-nothing
        if (c0 < NC) {
            const float4 v = *(const float4*)(rp + c0);
            x[4 * j] = v.x; x[4 * j + 1] = v.y; x[4 * j + 2] = v.z; x[4 * j + 3] = v.w;
        } else {
            x[4 * j] = x[4 * j + 1] = x[4 * j + 2] = x[4 * j + 3] = -INFINITY;
        }
    }
    float m = -INFINITY;
#pragma unroll
    for (int i = 0; i < 16; ++i) m = fmaxf(m, x[i]);
#pragma unroll
    for (int o = 1; o < 64; o <<= 1) m = fmaxf(m, __shfl_xor(m, o, 64));
    float s = 0.f;
#pragma unroll
    for (int i = 0; i < 16; ++i) s += expf(x[i] - m);
#pragma unroll
    for (int o = 1; o < 64; o <<= 1) s += __shfl_xor(s, o, 64);
    if (lane == 0) {
        int lab = labels[row];
        lab = lab < 0 ? 0 : (lab > NC - 1 ? NC - 1 : lab);
        atomicAdd(acc, (m + logf(s) - rp[lab]) * (1.0f / (float)NB));
    }
}

// ---------------- prototype Gram exp-sum (off-diagonal) ----------------
__global__ __launch_bounds__(256) void gram_kernel(const unsigned short* __restrict__ pbf,
                                                   float* __restrict__ acc) {
    __shared__ short8 atile[1024];
    const int t = threadIdx.x;
    const int wid = t >> 6, lane = t & 63;
    const int r16 = lane & 15, g = lane >> 4;
    const int irow = blockIdx.x * 64 + wid * 16 + r16;  // 0..1023 (pbf has 1024 rows)

    short8 bfrag[16];
    const unsigned short* ip = pbf + (size_t)irow * ND + 8 * g;
#pragma unroll
    for (int kk = 0; kk < 16; ++kk) bfrag[kk] = *(const short8*)(ip + 32 * kk);

    float s = 0.f;
    for (int ct = 0; ct < NTILES; ++ct) {
#pragma unroll
        for (int q = 0; q < 4; ++q) {
            const int id = t + 256 * q;
            const int rr = id & 15, gg = (id >> 4) & 3, kk = id >> 6;
            atile[id] = *(const short8*)(pbf + (size_t)(ct * 16 + rr) * ND + 32 * kk + 8 * gg);
        }
        __syncthreads();
        f32x4 dacc = {0.f, 0.f, 0.f, 0.f};
#pragma unroll
        for (int kk = 0; kk < 16; ++kk)
            dacc = __builtin_amdgcn_mfma_f32_16x16x32_bf16(atile[kk * 64 + lane], bfrag[kk], dacc, 0, 0, 0);
        __syncthreads();
        const int cbase = ct * 16 + g * 4;
        if (irow < NC) {
#pragma unroll
            for (int rI = 0; rI < 4; ++rI) {
                const int j = cbase + rI;
                if (j < NC && j != irow) s += expf(dacc[rI]);
            }
        }
    }
#pragma unroll
    for (int o = 1; o < 64; o <<= 1) s += __shfl_xor(s, o, 64);
    if (lane == 0) atomicAdd(acc, s);
}

// ---------------- final combine ----------------
__global__ void combine_kernel(const float* __restrict__ a, float* __restrict__ out) {
    // ALPHA*simloss + BETA*loss_ce + log(gram_sum)/NC   (ALPHA=BETA=1)
    out[0] = a[0] + a[1] + logf(a[2]) * (1.0f / (float)NC);
}

extern "C" void kernel_launch(void* const* d_in, const int* in_sizes, int n_in,
                              void* d_out, int out_size, void* d_ws, size_t ws_size,
                              hipStream_t stream) {
    const float* feat   = (const float*)d_in[0];  // [32768,512]
    const float* logits = (const float*)d_in[1];  // [32768,1000]
    const int*   labels = (const int*)d_in[2];    // [32768] (int32 per harness convention)
    const float* pro    = (const float*)d_in[3];  // [1000,512]
    float* out = (float*)d_out;

    float* acc = (float*)d_ws;                                  // [0]=sim,[1]=ce,[2]=gram
    unsigned short* pbf = (unsigned short*)((char*)d_ws + 64);  // [1024][512] bf16, ~1 MiB

    hipMemsetAsync(d_ws, 0, 64, stream);
    hipLaunchKernelGGL(norm_protos,    dim3(PROWS),      dim3(256), 0, stream, pro, pbf);
    hipLaunchKernelGGL(simloss_kernel, dim3(NB / 64),    dim3(256), 0, stream, feat, labels, pbf, acc);
    hipLaunchKernelGGL(ce_kernel,      dim3(NB / 4),     dim3(256), 0, stream, logits, labels, acc + 1);
    hipLaunchKernelGGL(gram_kernel,    dim3(PROWS / 64), dim3(256), 0, stream, pbf, acc + 2);
    hipLaunchKernelGGL(combine_kernel, dim3(1),          dim3(1),   0, stream, acc, out);
}

// Round 2
// 127.495 us; speedup vs baseline: 4.9137x; 4.9137x over previous
//
#include <hip/hip_runtime.h>
#include <math.h>

#define NB 32768
#define NC 1000
#define ND 512
#define NTILES 63          // 63*16 = 1008 >= 1000 class columns
#define PROWS 1024         // padded prototype rows stored in workspace
#define INV_T 10.0f        // 1/TEMPERATURE
#define NBUCKET 64         // accumulation buckets, strided 16 floats (64B)

typedef __attribute__((ext_vector_type(8))) short short8;
typedef __attribute__((ext_vector_type(4))) float f32x4;

__device__ __forceinline__ unsigned short bf16_rne(float f) {
    unsigned int u = __builtin_bit_cast(unsigned int, f);
    u += 0x7FFFu + ((u >> 16) & 1u);
    return (unsigned short)(u >> 16);
}

// ---------------- normalize prototypes -> bf16 [PROWS][ND] ----------------
__global__ __launch_bounds__(256) void norm_protos(const float* __restrict__ pro,
                                                   unsigned short* __restrict__ pbf) {
    const int row = blockIdx.x, t = threadIdx.x;
    unsigned int* dst = (unsigned int*)(pbf + (size_t)row * ND);
    if (row >= NC) { dst[t] = 0u; return; }  // zero pad rows (uniform per block)
    const float* rp = pro + (size_t)row * ND;
    const float x0 = rp[2 * t], x1 = rp[2 * t + 1];
    float ss = x0 * x0 + x1 * x1;
#pragma unroll
    for (int o = 1; o < 64; o <<= 1) ss += __shfl_xor(ss, o, 64);
    __shared__ float part[4];
    if ((t & 63) == 0) part[t >> 6] = ss;
    __syncthreads();
    const float nrm = sqrtf(part[0] + part[1] + part[2] + part[3]);
    const float sc = 1.0f / fmaxf(nrm, 1e-12f);
    dst[t] = (unsigned int)bf16_rne(x0 * sc) | ((unsigned int)bf16_rne(x1 * sc) << 16);
}

// Stage one 16-class x 512-k bf16 tile into LDS in fragment order [kk][g][r]
// via global_load_lds width=16 (dest = wave-uniform base + lane*16, linear).
__device__ __forceinline__ void stage_tile(const unsigned short* __restrict__ pbf,
                                           short8* buf, int ct, int t) {
#pragma unroll
    for (int q = 0; q < 4; ++q) {
        const int id = t + 256 * q;
        const int rr = id & 15, gg = (id >> 4) & 3, kk = id >> 6;
        const unsigned short* src = pbf + (size_t)(ct * 16 + rr) * ND + 32 * kk + 8 * gg;
        __builtin_amdgcn_global_load_lds(
            (const __attribute__((address_space(1))) unsigned int*)src,
            (__attribute__((address_space(3))) unsigned int*)(buf + id), 16, 0, 0);
    }
}

// ---------------- simloss: fused GEMM + online logsumexp ----------------
// Swapped MFMA: S^T = P_tile (A, 16x32) * F^T (B, 32x16) per K-step.
// D layout (m89-verified): col = lane&15 = feature row, row = (lane>>4)*4 + reg = class.
__global__ __launch_bounds__(256) void simloss_kernel(const float* __restrict__ feat,
                                                      const int* __restrict__ labels,
                                                      const unsigned short* __restrict__ pbf,
                                                      float* __restrict__ buckets) {
    __shared__ short8 atileA[1024];  // 16 KiB each, double-buffered
    __shared__ short8 atileB[1024];
    __shared__ float wsum[4];
    const int t = threadIdx.x;
    const int wid = t >> 6, lane = t & 63;
    const int r16 = lane & 15, g = lane >> 4;
    const int brow = blockIdx.x * 64 + wid * 16 + r16;

    // Convert this lane's feature-row slice to bf16 fragments (held across all C tiles)
    short8 bfrag[16];
    const float* fp = feat + (size_t)brow * ND + 8 * g;
#pragma unroll
    for (int kk = 0; kk < 16; ++kk) {
        const float4* p = (const float4*)(fp + 32 * kk);
        const float4 a = p[0], b = p[1];
        const float v[8] = {a.x, a.y, a.z, a.w, b.x, b.y, b.z, b.w};
        short8 s;
#pragma unroll
        for (int i = 0; i < 8; ++i) s[i] = (short)bf16_rne(v[i]);
        bfrag[kk] = s;
    }

    int lab = labels[brow];
    lab = lab < 0 ? 0 : (lab > NC - 1 ? NC - 1 : lab);

    float m = -INFINITY, lsum = 0.f, labv = 0.f;

    short8* curb = atileA;
    short8* nxtb = atileB;
    stage_tile(pbf, curb, 0, t);
    __syncthreads();  // full vmcnt drain: tile 0 resident

    for (int ct = 0; ct < NTILES; ++ct) {
        if (ct + 1 < NTILES) stage_tile(pbf, nxtb, ct + 1, t);  // in flight during compute

        f32x4 dacc = {0.f, 0.f, 0.f, 0.f};
#pragma unroll
        for (int kk = 0; kk < 16; ++kk)
            dacc = __builtin_amdgcn_mfma_f32_16x16x32_bf16(curb[kk * 64 + lane], bfrag[kk], dacc, 0, 0, 0);

        const int cbase = ct * 16 + g * 4;
        float vv[4], tmax = -INFINITY;
#pragma unroll
        for (int rI = 0; rI < 4; ++rI) {
            const int c = cbase + rI;
            const float v = dacc[rI] * INV_T;
            const bool ok = (c < NC);
            if (ok && c == lab) labv += v;
            vv[rI] = ok ? v : -INFINITY;
            tmax = fmaxf(tmax, vv[rI]);
        }
        if (tmax > m) {            // defer-max: rescale only on new max (rare after warmup)
            lsum *= expf(m - tmax);  // expf(-inf)=0 handles the first tile
            m = tmax;
        }
        float add = 0.f;
#pragma unroll
        for (int rI = 0; rI < 4; ++rI) add += expf(vv[rI] - m);
        lsum += add;

        __syncthreads();  // drains prefetch (vmcnt) + all waves done reading curb
        short8* tmp = curb; curb = nxtb; nxtb = tmp;
    }

    // Combine the 4 lane-groups holding the same feature row (xor 16, xor 32)
#pragma unroll
    for (int o = 16; o <= 32; o <<= 1) {
        const float mo = __shfl_xor(m, o, 64);
        const float lo = __shfl_xor(lsum, o, 64);
        labv += __shfl_xor(labv, o, 64);
        const float mm = fmaxf(m, mo);
        lsum = lsum * expf(m - mm) + lo * expf(mo - mm);
        m = mm;
    }
    // Each row's value now replicated on 4 lanes -> scale by 1/4, then mean over B
    float mine = (m + logf(lsum) - labv) * (1.0f / (4.0f * (float)NB));
#pragma unroll
    for (int o = 1; o < 64; o <<= 1) mine += __shfl_xor(mine, o, 64);
    if (lane == 0) wsum[wid] = mine;
    __syncthreads();
    if (t == 0)
        atomicAdd(buckets + (blockIdx.x & (NBUCKET - 1)) * 16,
                  wsum[0] + wsum[1] + wsum[2] + wsum[3]);
}

// ---------------- cross-entropy over logits ----------------
__global__ __launch_bounds__(256) void ce_kernel(const float* __restrict__ logits,
                                                 const int* __restrict__ labels,
                                                 float* __restrict__ buckets) {
    __shared__ float wsum[4];
    const int t = threadIdx.x, wid = t >> 6, lane = t & 63;
    const int wgid = blockIdx.x * 4 + wid;  // 4096 waves, grid-stride 8 rows each
    float local = 0.f;

    for (int row = wgid; row < NB; row += 4096) {
        const float* rp = logits + (size_t)row * NC;
        float x[16];
#pragma unroll
        for (int j = 0; j < 4; ++j) {
            const int c0 = lane * 4 + j * 256;  // float4-granular; 1000%4==0
            if (c0 < NC) {
                const float4 v = *(const float4*)(rp + c0);
                x[4 * j] = v.x; x[4 * j + 1] = v.y; x[4 * j + 2] = v.z; x[4 * j + 3] = v.w;
            } else {
                x[4 * j] = x[4 * j + 1] = x[4 * j + 2] = x[4 * j + 3] = -INFINITY;
            }
        }
        float m = -INFINITY;
#pragma unroll
        for (int i = 0; i < 16; ++i) m = fmaxf(m, x[i]);
#pragma unroll
        for (int o = 1; o < 64; o <<= 1) m = fmaxf(m, __shfl_xor(m, o, 64));
        float s = 0.f;
#pragma unroll
        for (int i = 0; i < 16; ++i) s += expf(x[i] - m);
#pragma unroll
        for (int o = 1; o < 64; o <<= 1) s += __shfl_xor(s, o, 64);
        int lab = labels[row];
        lab = lab < 0 ? 0 : (lab > NC - 1 ? NC - 1 : lab);
        local += m + logf(s) - rp[lab];  // identical on all 64 lanes
    }
    if (lane == 0) wsum[wid] = local;
    __syncthreads();
    if (t == 0)
        atomicAdd(buckets + (blockIdx.x & (NBUCKET - 1)) * 16,
                  (wsum[0] + wsum[1] + wsum[2] + wsum[3]) * (1.0f / (float)NB));
}

// ---------------- prototype Gram exp-sum (off-diagonal) ----------------
// pbf (1 MiB) is L2-resident: read fragments directly, no LDS staging.
__global__ __launch_bounds__(256) void gram_kernel(const unsigned short* __restrict__ pbf,
                                                   float* __restrict__ buckets) {
    __shared__ float wsum[4];
    const int t = threadIdx.x;
    const int wid = t >> 6, lane = t & 63;
    const int r16 = lane & 15, g = lane >> 4;
    const int ct = blockIdx.y;                           // class tile 0..62
    const int irow = blockIdx.x * 64 + wid * 16 + r16;   // 0..1023 (pad rows are zeros)

    short8 bfrag[16], afrag[16];
    const unsigned short* ip = pbf + (size_t)irow * ND + 8 * g;
    const unsigned short* ap = pbf + (size_t)(ct * 16 + r16) * ND + 8 * g;
#pragma unroll
    for (int kk = 0; kk < 16; ++kk) {
        bfrag[kk] = *(const short8*)(ip + 32 * kk);
        afrag[kk] = *(const short8*)(ap + 32 * kk);
    }
    f32x4 dacc = {0.f, 0.f, 0.f, 0.f};
#pragma unroll
    for (int kk = 0; kk < 16; ++kk)
        dacc = __builtin_amdgcn_mfma_f32_16x16x32_bf16(afrag[kk], bfrag[kk], dacc, 0, 0, 0);

    float s = 0.f;
    if (irow < NC) {
        const int cbase = ct * 16 + g * 4;
#pragma unroll
        for (int rI = 0; rI < 4; ++rI) {
            const int j = cbase + rI;
            if (j < NC && j != irow) s += expf(dacc[rI]);
        }
    }
#pragma unroll
    for (int o = 1; o < 64; o <<= 1) s += __shfl_xor(s, o, 64);
    if (lane == 0) wsum[wid] = s;
    __syncthreads();
    if (t == 0)
        atomicAdd(buckets + ((blockIdx.x + 16 * blockIdx.y) & (NBUCKET - 1)) * 16,
                  wsum[0] + wsum[1] + wsum[2] + wsum[3]);
}

// ---------------- final combine: sum buckets ----------------
__global__ void combine_kernel(const float* __restrict__ a, float* __restrict__ out) {
    const int t = threadIdx.x;  // 64 threads
    float s = a[t * 16], c = a[1024 + t * 16], gr = a[2048 + t * 16];
#pragma unroll
    for (int o = 1; o < 64; o <<= 1) {
        s += __shfl_xor(s, o, 64);
        c += __shfl_xor(c, o, 64);
        gr += __shfl_xor(gr, o, 64);
    }
    if (t == 0) out[0] = s + c + logf(gr) * (1.0f / (float)NC);
}

extern "C" void kernel_launch(void* const* d_in, const int* in_sizes, int n_in,
                              void* d_out, int out_size, void* d_ws, size_t ws_size,
                              hipStream_t stream) {
    const float* feat   = (const float*)d_in[0];  // [32768,512]
    const float* logits = (const float*)d_in[1];  // [32768,1000]
    const int*   labels = (const int*)d_in[2];    // [32768]
    const float* pro    = (const float*)d_in[3];  // [1000,512]
    float* out = (float*)d_out;

    float* acc = (float*)d_ws;  // 3 bucket arrays: [0]=sim, [1024]=ce, [2048]=gram (stride-16 floats)
    unsigned short* pbf = (unsigned short*)((char*)d_ws + 16384);  // [1024][512] bf16, 1 MiB

    hipMemsetAsync(d_ws, 0, 3072 * sizeof(float), stream);
    hipLaunchKernelGGL(norm_protos,    dim3(PROWS),        dim3(256), 0, stream, pro, pbf);
    hipLaunchKernelGGL(simloss_kernel, dim3(NB / 64),      dim3(256), 0, stream, feat, labels, pbf, acc);
    hipLaunchKernelGGL(ce_kernel,      dim3(1024),         dim3(256), 0, stream, logits, labels, acc + 1024);
    hipLaunchKernelGGL(gram_kernel,    dim3(16, NTILES),   dim3(256), 0, stream, pbf, acc + 2048);
    hipLaunchKernelGGL(combine_kernel, dim3(1),            dim3(64),  0, stream, acc, out);
}